// Round 9
// baseline (645.912 us; speedup 1.0000x reference)
//
#include <hip/hip_runtime.h>
#include <hip/hip_bf16.h>
#include <math.h>

#define EPS 1e-5f

typedef __attribute__((ext_vector_type(8))) _Float16 half8;
typedef __attribute__((ext_vector_type(2))) _Float16 half2v;
typedef __attribute__((ext_vector_type(4))) float f32x4;

static __device__ __forceinline__ unsigned short f16u(float x) {
  _Float16 h = (_Float16)x;
  return *(unsigned short*)&h;
}
static __device__ __forceinline__ float uf16(unsigned short u) {
  _Float16 h = *(_Float16*)&u;
  return (float)h;
}
static __device__ __forceinline__ float fdot2f(half2v a, half2v b, float c) {
#if __has_builtin(__builtin_amdgcn_fdot2)
  return __builtin_amdgcn_fdot2(a, b, c, false);
#else
  return c + (float)a[0] * (float)b[0] + (float)a[1] * (float)b[1];
#endif
}

// ---------------- Fused conv1(+bn1+leaky+pool) in-register + conv2 MFMA (+bn2+leaky+pool) ----------------
// x [256][4096][2] -> out2 f16 [256][1022][64]. Weight transform done in-block from w2.
__global__ __launch_bounds__(512) void kConv12(const float* __restrict__ x,
    const float* __restrict__ w1a, const float* __restrict__ w1b,
    const float* __restrict__ g1, const float* __restrict__ b1,
    const float* __restrict__ m1, const float* __restrict__ v1,
    const float* __restrict__ w2, const float* __restrict__ g2,
    const float* __restrict__ b2, const float* __restrict__ m2,
    const float* __restrict__ v2, unsigned short* __restrict__ out2) {
  __shared__ _Float16 sA[130 * 40];
  __shared__ _Float16 sB[64 * 104];
  int tid = threadIdx.x;
  int b = blockIdx.z;
  int p0 = blockIdx.x * 128;
  // stage conv2 weights: sB[oc*104 + k*32+ci] = w2[oc][ci][k]
  for (int i = tid; i < 64 * 104; i += 512) {
    int oc = i / 104, kp = i - oc * 104;
    float v = 0.f;
    if (kp < 96) v = w2[oc * 96 + (kp & 31) * 3 + (kp >> 5)];
    sB[i] = (_Float16)v;
  }
  // conv1 + bn1 + leaky + pool directly into sA (f16)
  {
    int c = tid & 31, rg = tid >> 5;
    float sc1 = g1[c] * rsqrtf(v1[c] + EPS);
    float sh1 = b1[c] - m1[c] * sc1;
    float wk0[4], wk1[4];
    if (c < 16) {
#pragma unroll
      for (int k = 0; k < 4; k++) { wk0[k] = w1a[c * 8 + k]; wk1[k] = w1a[c * 8 + 4 + k]; }
    } else {
      int cc = c - 16;
#pragma unroll
      for (int k = 0; k < 2; k++) { wk0[k] = w1b[cc * 4 + k]; wk1[k] = w1b[cc * 4 + 2 + k]; }
      wk0[2] = wk0[3] = wk1[2] = wk1[3] = 0.f;
    }
    const float2* xp = (const float2*)(x + (size_t)b * 8192);
    for (int r = rg; r < 130; r += 16) {
      int rr = p0 + r;
      _Float16 outv = (_Float16)0.f;
      if (rr < 2047) {
        float xv0[5], xv1[5];
#pragma unroll
        for (int j = 0; j < 5; j++) {
          int l = 2 * rr - 1 + j;
          if (l >= 0 && l < 4096) { float2 v = xp[l]; xv0[j] = v.x; xv1[j] = v.y; }
          else { xv0[j] = 0.f; xv1[j] = 0.f; }
        }
        float a0 = 0.f, a1 = 0.f;
        if (c < 16) {
#pragma unroll
          for (int k = 0; k < 4; k++) {
            a0 += xv0[k] * wk0[k] + xv1[k] * wk1[k];
            a1 += xv0[k + 1] * wk0[k] + xv1[k + 1] * wk1[k];
          }
        } else {
#pragma unroll
          for (int k = 0; k < 2; k++) {
            a0 += xv0[k + 1] * wk0[k] + xv1[k + 1] * wk1[k];
            a1 += xv0[k + 2] * wk0[k] + xv1[k + 2] * wk1[k];
          }
        }
        a0 = a0 * sc1 + sh1; a1 = a1 * sc1 + sh1;
        a0 = a0 >= 0.f ? a0 : 0.01f * a0;
        a1 = a1 >= 0.f ? a1 : 0.01f * a1;
        outv = (_Float16)fmaxf(a0, a1);
      }
      sA[r * 40 + c] = outv;
    }
  }
  __syncthreads();
  int lane = tid & 63, w = tid >> 6;
  int nrow = lane & 15, quad = lane >> 4;
  f32x4 acc[4];
#pragma unroll
  for (int i = 0; i < 4; i++) acc[i] = (f32x4){0.f, 0.f, 0.f, 0.f};
  int mbase = w * 16;
#pragma unroll
  for (int kk = 0; kk < 3; kk++) {
    half8 a = *(const half8*)(sA + (mbase + nrow + kk) * 40 + quad * 8);
#pragma unroll
    for (int ot = 0; ot < 4; ot++) {
      half8 bb = *(const half8*)(sB + (ot * 16 + nrow) * 104 + kk * 32 + quad * 8);
      acc[ot] = __builtin_amdgcn_mfma_f32_16x16x32_f16(a, bb, acc[ot], 0, 0, 0);
    }
  }
  int gm0 = p0 + mbase + quad * 4;
#pragma unroll
  for (int ot = 0; ot < 4; ot++) {
    int oc = ot * 16 + nrow;
    float sc = g2[oc] * rsqrtf(v2[oc] + EPS);
    float sh = b2[oc] - m2[oc] * sc;
    float v0 = acc[ot][0] * sc + sh, vv1 = acc[ot][1] * sc + sh;
    float v2e = acc[ot][2] * sc + sh, v3 = acc[ot][3] * sc + sh;
    v0 = v0 >= 0.f ? v0 : 0.01f * v0;
    vv1 = vv1 >= 0.f ? vv1 : 0.01f * vv1;
    v2e = v2e >= 0.f ? v2e : 0.01f * v2e;
    v3 = v3 >= 0.f ? v3 : 0.01f * v3;
    float pA = fmaxf(v0, vv1), pB = fmaxf(v2e, v3);
    int t0 = gm0 >> 1, t1 = t0 + 1;
    if (t0 < 1022) out2[((size_t)b * 1022 + t0) * 64 + oc] = f16u(pA);
    if (t1 < 1022) out2[((size_t)b * 1022 + t1) * 64 + oc] = f16u(pB);
  }
}

// ---------------- MFMA conv3 + bn + leaky + pool + LayerNorm fused -> xn f16, elast ----------------
__global__ __launch_bounds__(512) void kConv3LN(const unsigned short* __restrict__ in,
    const float* __restrict__ w3, const float* __restrict__ g,
    const float* __restrict__ bta, const float* __restrict__ mn,
    const float* __restrict__ vr, const float* __restrict__ lnw,
    unsigned short* __restrict__ xn, float* __restrict__ elast) {
  constexpr int IC = 64, OC = 128, LIN = 1022, AP = 72, BP = 200, KSTEPS = 6, OCT = 8;
  __shared__ _Float16 sA[130 * AP];
  __shared__ _Float16 sB[OC * BP];
  int tid = threadIdx.x;
  int b = blockIdx.z;
  int p0 = blockIdx.x * 128;
  // stage conv3 weights: sB[oc*200 + k*64+ci] = w3[oc][ci][k]
  for (int i = tid; i < 128 * 200; i += 512) {
    int oc = i / 200, kp = i - oc * 200;
    float v = 0.f;
    if (kp < 192) v = w3[oc * 192 + (kp & 63) * 3 + (kp >> 6)];
    sB[i] = (_Float16)v;
  }
  {
    int q = tid % 8;
    for (int r = tid / 8; r < 130; r += 64) {
      int gp = p0 + r;
      uint4 val = {0u, 0u, 0u, 0u};
      if (gp < LIN) val = *(const uint4*)(in + ((size_t)b * LIN + gp) * IC + q * 8);
      *(uint4*)(sA + r * AP + q * 8) = val;
    }
  }
  __syncthreads();
  int lane = tid & 63, w = tid >> 6;
  int nrow = lane & 15, quad = lane >> 4;
  f32x4 acc[OCT];
#pragma unroll
  for (int i = 0; i < OCT; i++) acc[i] = (f32x4){0.f, 0.f, 0.f, 0.f};
  int mbase = w * 16;
#pragma unroll
  for (int kk = 0; kk < KSTEPS; kk++) {
    int k = kk >> 1;
    int ci0 = (kk & 1) * 32;
    half8 a = *(const half8*)(sA + (mbase + nrow + k) * AP + ci0 + quad * 8);
#pragma unroll
    for (int ot = 0; ot < OCT; ot++) {
      half8 bb = *(const half8*)(sB + (ot * 16 + nrow) * BP + kk * 32 + quad * 8);
      acc[ot] = __builtin_amdgcn_mfma_f32_16x16x32_f16(a, bb, acc[ot], 0, 0, 0);
    }
  }
  float pA[OCT], pB[OCT];
  float sA1 = 0.f, sA2 = 0.f, sB1 = 0.f, sB2 = 0.f;
#pragma unroll
  for (int ot = 0; ot < OCT; ot++) {
    int oc = ot * 16 + nrow;
    float sc = g[oc] * rsqrtf(vr[oc] + EPS);
    float sh = bta[oc] - mn[oc] * sc;
    float v0 = acc[ot][0] * sc + sh, v1 = acc[ot][1] * sc + sh;
    float v2 = acc[ot][2] * sc + sh, v3 = acc[ot][3] * sc + sh;
    v0 = v0 >= 0.f ? v0 : 0.01f * v0;
    v1 = v1 >= 0.f ? v1 : 0.01f * v1;
    v2 = v2 >= 0.f ? v2 : 0.01f * v2;
    v3 = v3 >= 0.f ? v3 : 0.01f * v3;
    float a = fmaxf(v0, v1), bb2 = fmaxf(v2, v3);
    pA[ot] = a; pB[ot] = bb2;
    sA1 += a; sA2 += a * a; sB1 += bb2; sB2 += bb2 * bb2;
  }
#pragma unroll
  for (int m = 1; m <= 8; m <<= 1) {
    sA1 += __shfl_xor(sA1, m); sA2 += __shfl_xor(sA2, m);
    sB1 += __shfl_xor(sB1, m); sB2 += __shfl_xor(sB2, m);
  }
  float muA = sA1 * (1.f / 128.f);
  float rsA = rsqrtf(sA2 * (1.f / 128.f) - muA * muA + EPS);
  float muB = sB1 * (1.f / 128.f);
  float rsB = rsqrtf(sB2 * (1.f / 128.f) - muB * muB + EPS);
  int t0 = (p0 + mbase + quad * 4) >> 1, t1 = t0 + 1;
#pragma unroll
  for (int ot = 0; ot < OCT; ot++) {
    int oc = ot * 16 + nrow;
    float lw = lnw[oc];
    if (t0 < 510) xn[((size_t)b * 510 + t0) * OC + oc] = f16u((pA[ot] - muA) * rsA * lw);
    if (t1 < 510) xn[((size_t)b * 510 + t1) * OC + oc] = f16u((pB[ot] - muB) * rsB * lw);
    if (t1 == 509) elast[b * 128 + oc] = pB[ot];
  }
}

// ---------------- Fused dwconv+SiLU + gate projections via MFMA (f16) ----------------
__global__ __launch_bounds__(256) void kGxM(const unsigned short* __restrict__ xn,
    const float* __restrict__ cw, const float* __restrict__ cb,
    const float* __restrict__ wi, const float* __restrict__ wf,
    const float* __restrict__ wz, const float* __restrict__ wo,
    const float* __restrict__ rb, unsigned int* __restrict__ gx) {
  __shared__ __align__(16) char smem[29200];
  float* xnf = (float*)smem;                  // [66][33] fp32
  _Float16* aX = (_Float16*)(smem + 8720);    // [64][40] f16 xcv
  _Float16* aN = (_Float16*)(smem + 13840);   // [64][40] f16 xn
  unsigned short* ct = (unsigned short*)smem; // [64][132] C-transpose (aliases above)
  _Float16* sW = (_Float16*)(smem + 18960);   // [2][64][40] weights
  int bh = blockIdx.x, b = bh >> 2, h = bh & 3;
  int tid = threadIdx.x, lane = tid & 63, w = tid >> 6;
  int nrow = lane & 15, quad = lane >> 4;
  for (int idx = tid; idx < 4096; idx += 256) {
    int slot = idx >> 11, n = (idx >> 5) & 63, d = idx & 31;
    const float* wp = slot ? ((n >= 32) ? wo : wz) : ((n >= 32) ? wf : wi);
    sW[slot * 2560 + n * 40 + d] = (_Float16)wp[h * 1024 + d * 32 + (n & 31)];
  }
  int dd = tid & 31;
  float cw0 = cw[(h * 32 + dd) * 3], cw1 = cw[(h * 32 + dd) * 3 + 1],
        cw2 = cw[(h * 32 + dd) * 3 + 2], cbv = cb[h * 32 + dd];
  float bias0[4], bias1[4];
#pragma unroll
  for (int nt = 0; nt < 4; nt++) {
    int n = nt * 16 + nrow;
    bias0[nt] = rb[(n >> 5) * 128 + h * 32 + (n & 31)];
    bias1[nt] = rb[(2 + (n >> 5)) * 128 + h * 32 + (n & 31)];
  }
  __syncthreads();
  half8 bw0[4], bw1[4];
#pragma unroll
  for (int nt = 0; nt < 4; nt++) {
    bw0[nt] = *(const half8*)(sW + (nt * 16 + nrow) * 40 + quad * 8);
    bw1[nt] = *(const half8*)(sW + 2560 + (nt * 16 + nrow) * 40 + quad * 8);
  }
  const unsigned short* xb = xn + ((size_t)b * 510) * 128 + h * 32;
  for (int s0 = 0; s0 < 510; s0 += 64) {
    __syncthreads();
    {
      int d2 = tid & 15;
      for (int r = tid >> 4; r < 66; r += 16) {
        int s = s0 - 2 + r;
        unsigned int v = 0;
        if (s >= 0 && s < 510) v = *(const unsigned int*)(xb + (size_t)s * 128 + d2 * 2);
        xnf[r * 33 + d2 * 2]     = uf16(v & 0xFFFFu);
        xnf[r * 33 + d2 * 2 + 1] = uf16(v >> 16);
      }
    }
    __syncthreads();
    for (int m = tid >> 5; m < 64; m += 8) {
      float x0 = xnf[m * 33 + dd], x1 = xnf[(m + 1) * 33 + dd], x2 = xnf[(m + 2) * 33 + dd];
      float a = cbv + cw0 * x0 + cw1 * x1 + cw2 * x2;
      a = a * __builtin_amdgcn_rcpf(1.f + __expf(-a));
      aX[m * 40 + dd] = (_Float16)a;
      aN[m * 40 + dd] = (_Float16)x2;
    }
    __syncthreads();
    f32x4 z = (f32x4){0.f, 0.f, 0.f, 0.f};
    half8 ax = *(const half8*)(aX + (w * 16 + nrow) * 40 + quad * 8);
    half8 an = *(const half8*)(aN + (w * 16 + nrow) * 40 + quad * 8);
    f32x4 acc0[4], acc1[4];
#pragma unroll
    for (int nt = 0; nt < 4; nt++) {
      acc0[nt] = __builtin_amdgcn_mfma_f32_16x16x32_f16(ax, bw0[nt], z, 0, 0, 0);
      acc1[nt] = __builtin_amdgcn_mfma_f32_16x16x32_f16(an, bw1[nt], z, 0, 0, 0);
    }
    __syncthreads();
#pragma unroll
    for (int nt = 0; nt < 4; nt++) {
#pragma unroll
      for (int r = 0; r < 4; r++) {
        int row = w * 16 + quad * 4 + r;
        ct[row * 132 + 2 * (nt * 16 + nrow)]     = f16u(acc0[nt][r] + bias0[nt]);
        ct[row * 132 + 2 * (nt * 16 + nrow) + 1] = f16u(acc1[nt][r] + bias1[nt]);
      }
    }
    __syncthreads();
    {
      int u = tid & 63;
      for (int m = tid >> 6; m < 64; m += 4) {
        int s = s0 + m;
        if (s < 510)
          gx[((size_t)s * 1024 + bh) * 64 + u] = *(const unsigned int*)(ct + m * 132 + 2 * u);
      }
    }
  }
}

// ---------------- sLSTM recurrence: LDS f16 y-broadcast + fdot2 matvec ----------------
// wave=(b,h); half=l>>5, e=l&31. half0: i(a1)/z(a2); half1: f(a1)/o(a2). One wave per block.
__global__ __launch_bounds__(64) void kRec(const unsigned int* __restrict__ gx,
    const float* __restrict__ rk, float* __restrict__ yf) {
  __shared__ _Float16 ybuf[64];
  int bh = blockIdx.x; int h = bh & 3;
  int l = threadIdx.x; int half = l >> 5; int e = l & 31;
  half2v R1p[16], R2p[16];
  int g1 = half, g2 = 2 + half;
  const float* r1p = rk + h * 4096 + g1 * 32 + e;
  const float* r2p = rk + h * 4096 + g2 * 32 + e;
#pragma unroll
  for (int d = 0; d < 16; d++) {
    R1p[d] = (half2v){(_Float16)r1p[(2 * d) * 128], (_Float16)r1p[(2 * d + 1) * 128]};
    R2p[d] = (half2v){(_Float16)r2p[(2 * d) * 128], (_Float16)r2p[(2 * d + 1) * 128]};
  }
  const unsigned int* gp = gx + (size_t)bh * 64 + l;
  unsigned int p0 = gp[0], p1 = gp[65536], p2 = gp[131072], p3 = gp[196608];
  float y = 0.f, cst = 0.f, nst = 0.f, mst = 0.f;
  ybuf[l] = (_Float16)0.f;  // single wave/block: in-order LDS, no barrier needed
  for (int s = 0; s < 510; s++) {
    unsigned int pc = p0; p0 = p1; p1 = p2; p2 = p3;
    if (s + 4 < 510) p3 = gp[(size_t)(s + 4) * 65536];
    float a1 = uf16(pc & 0xFFFFu);   // pre (i/f)
    float a2 = uf16(pc >> 16);       // pre (z/o)
    // y broadcast: read y[0..31] (64 B) at wave-uniform address — 4x ds_read_b128
    _Float16 yl[32];
    *(half8*)(yl)      = *(const half8*)(ybuf);
    *(half8*)(yl + 8)  = *(const half8*)(ybuf + 8);
    *(half8*)(yl + 16) = *(const half8*)(ybuf + 16);
    *(half8*)(yl + 24) = *(const half8*)(ybuf + 24);
    float s1a = 0.f, s1b = 0.f, s2a = 0.f, s2b = 0.f;
#pragma unroll
    for (int d = 0; d < 16; d += 2) {
      half2v ya = *(const half2v*)(yl + 2 * d);
      half2v yb = *(const half2v*)(yl + 2 * d + 2);
      s1a = fdot2f(ya, R1p[d], s1a);
      s1b = fdot2f(yb, R1p[d + 1], s1b);
      s2a = fdot2f(ya, R2p[d], s2a);
      s2b = fdot2f(yb, R2p[d + 1], s2b);
    }
    a1 += s1a + s1b;
    a2 += s2a + s2b;
    float en = __expf(-fabsf(a1));
    float ls = fminf(a1, 0.f) - __logf(1.f + en);        // log-sigmoid(a1)
    float u = half ? a2 : (a2 + a2);                     // half1: σ(o); half0: tanh via σ(2z)
    float su = __builtin_amdgcn_rcpf(1.f + __expf(-u));
    float tz = su + su - 1.f;                            // tanh(a2) on half0
    float lsf = __shfl_xor(ls, 32);                      // logsig(fraw) -> half0
    float so  = __shfl_xor(su, 32);                      // σ(oraw) -> half0
    float lf = mst + lsf;
    float mnew = fmaxf(a1, lf);                          // a1 = iraw on half0
    float ig = __expf(a1 - mnew);
    float fg = __expf(lf - mnew);
    cst = fg * cst + ig * tz;
    nst = fg * nst + ig;
    mst = mnew;
    y = so * cst * __builtin_amdgcn_rcpf(nst);
    ybuf[l] = (_Float16)y;  // lanes 0..31 real; 32..63 dummy (never read)
  }
  if (half == 0) yf[(bh >> 2) * 128 + h * 32 + e] = y;
}

// ---------------- Tail for the last timestep only ----------------
__global__ __launch_bounds__(128) void kHead(const float* __restrict__ yf,
    const float* __restrict__ elast, const float* __restrict__ gnw,
    const float* __restrict__ ln2w, const float* __restrict__ upw,
    const float* __restrict__ dnw, const float* __restrict__ lnpw,
    const float* __restrict__ fcw, const float* __restrict__ fcb,
    float* __restrict__ outp) {
  int c = threadIdx.x; int b = blockIdx.x;
  __shared__ float sred[4];
  __shared__ float sx[128];
  __shared__ float sup[384];
  __shared__ float shh[192];
  float yv = yf[b * 128 + c];
  float s1 = yv, s2 = yv * yv;
#pragma unroll
  for (int m = 1; m <= 16; m <<= 1) { s1 += __shfl_xor(s1, m); s2 += __shfl_xor(s2, m); }
  float mu = s1 * (1.f / 32.f);
  float var = s2 * (1.f / 32.f) - mu * mu;
  float yn = (yv - mu) * rsqrtf(var + EPS) * gnw[c];
  float el = elast[b * 128 + c] + yn;
  auto ln128 = [&](float v, const float* w) -> float {
    float a = v, a2 = v * v;
#pragma unroll
    for (int m = 1; m <= 32; m <<= 1) { a += __shfl_xor(a, m); a2 += __shfl_xor(a2, m); }
    int wv = c >> 6;
    if ((c & 63) == 0) { sred[wv * 2] = a; sred[wv * 2 + 1] = a2; }
    __syncthreads();
    float t1 = sred[0] + sred[2], t2 = sred[1] + sred[3];
    __syncthreads();
    float mm = t1 * (1.f / 128.f);
    float vv = t2 * (1.f / 128.f) - mm * mm;
    return (v - mm) * rsqrtf(vv + EPS) * w[c];
  };
  float xn2 = ln128(el, ln2w);
  sx[c] = xn2;
  __syncthreads();
#pragma unroll
  for (int jj = 0; jj < 3; jj++) {
    int j = c + jj * 128;
    float acc = 0.f;
    for (int k = 0; k < 128; k++) acc += sx[k] * upw[k * 384 + j];
    sup[j] = acc;
  }
  __syncthreads();
  {
    float u = sup[c]; float mg = sup[192 + c];
    shh[c] = 0.5f * u * (1.f + erff(u * 0.70710678118654752f)) * mg;
    if (c < 64) {
      float u2 = sup[128 + c]; float m2 = sup[320 + c];
      shh[128 + c] = 0.5f * u2 * (1.f + erff(u2 * 0.70710678118654752f)) * m2;
    }
  }
  __syncthreads();
  float acc = 0.f;
  for (int f = 0; f < 192; f++) acc += shh[f] * dnw[f * 128 + c];
  float e2 = el + acc;
  float e3 = ln128(e2, lnpw);
  sx[c] = e3;
  __syncthreads();
  if (c < 5) {
    float a = fcb[c];
    for (int k = 0; k < 128; k++) a += sx[k] * fcw[k * 5 + c];
    outp[b * 5 + c] = a;
  }
}

extern "C" void kernel_launch(void* const* d_in, const int* in_sizes, int n_in,
                              void* d_out, int out_size, void* d_ws, size_t ws_size,
                              hipStream_t stream) {
  const float* x    = (const float*)d_in[0];
  const float* w1a  = (const float*)d_in[1];
  const float* w1b  = (const float*)d_in[2];
  const float* bn1g = (const float*)d_in[3];
  const float* bn1b = (const float*)d_in[4];
  const float* bn1m = (const float*)d_in[5];
  const float* bn1v = (const float*)d_in[6];
  const float* w2   = (const float*)d_in[7];
  const float* bn2g = (const float*)d_in[8];
  const float* bn2b = (const float*)d_in[9];
  const float* bn2m = (const float*)d_in[10];
  const float* bn2v = (const float*)d_in[11];
  const float* w3   = (const float*)d_in[12];
  const float* bn3g = (const float*)d_in[13];
  const float* bn3b = (const float*)d_in[14];
  const float* bn3m = (const float*)d_in[15];
  const float* bn3v = (const float*)d_in[16];
  const float* ln1w = (const float*)d_in[17];
  const float* cw   = (const float*)d_in[18];
  const float* cb   = (const float*)d_in[19];
  const float* wi   = (const float*)d_in[20];
  const float* wf   = (const float*)d_in[21];
  const float* wz   = (const float*)d_in[22];
  const float* wo   = (const float*)d_in[23];
  const float* rk   = (const float*)d_in[24];
  const float* rb   = (const float*)d_in[25];
  const float* gnw  = (const float*)d_in[26];
  const float* ln2w = (const float*)d_in[27];
  const float* upw  = (const float*)d_in[28];
  const float* dnw  = (const float*)d_in[29];
  const float* lnpw = (const float*)d_in[30];
  const float* fcw  = (const float*)d_in[31];
  const float* fcb  = (const float*)d_in[32];
  float* outp = (float*)d_out;

  char* ws = (char*)d_ws;
  unsigned short* xnb  = (unsigned short*)ws;                         // [256][510][128] f16 33.4MB
  unsigned short* out2 = (unsigned short*)(ws + ((size_t)64 << 20));  // [256][1022][64] f16 33.5MB
  unsigned int*   gxu  = (unsigned int*)(ws + ((size_t)128 << 20));   // gx f16-pairs 133.7MB
  float* elast = (float*)(ws + ((size_t)258 << 20));
  float* yfin  = (float*)(ws + ((size_t)259 << 20));

  kConv12<<<dim3(16, 1, 256), 512, 0, stream>>>(
      x, w1a, w1b, bn1g, bn1b, bn1m, bn1v, w2, bn2g, bn2b, bn2m, bn2v, out2);
  kConv3LN<<<dim3(8, 1, 256), 512, 0, stream>>>(
      out2, w3, bn3g, bn3b, bn3m, bn3v, ln1w, xnb, elast);
  kGxM<<<dim3(1024), 256, 0, stream>>>(xnb, cw, cb, wi, wf, wz, wo, rb, gxu);
  kRec<<<dim3(1024), 64, 0, stream>>>(gxu, rk, yfin);
  kHead<<<dim3(256), 128, 0, stream>>>(yfin, elast, gnw, ln2w, upw, dnw, lnpw, fcw, fcb, outp);
}